// Round 12
// baseline (20827.028 us; speedup 1.0000x reference)
//
#include <hip/hip_runtime.h>
#include <hip/hip_bf16.h>
#include <hip/hip_fp16.h>

// Problem sizes
#define NB 32
#define NT 256
#define NH 256
#define NV 32000
#define NL2 512     // fixed KV length = 2T
#define NTP1 257    // T+1

typedef unsigned int u32x4 __attribute__((ext_vector_type(4)));
typedef short s16x8 __attribute__((ext_vector_type(8)));
typedef float f32x4 __attribute__((ext_vector_type(4)));
typedef _Float16 half2v __attribute__((ext_vector_type(2)));

#define AGENT __HIP_MEMORY_SCOPE_AGENT
__device__ __forceinline__ float aload(const float* p) {
  return __hip_atomic_load((float*)p, __ATOMIC_RELAXED, AGENT);
}
__device__ __forceinline__ void astore(float* p, float v) {
  __hip_atomic_store(p, v, __ATOMIC_RELAXED, AGENT);
}

__device__ __forceinline__ float dot2f(half2v a, half2v b, float c) {
#if __has_builtin(__builtin_amdgcn_fdot2)
  return __builtin_amdgcn_fdot2(a, b, c, false);
#else
  return c + (float)a[0] * (float)b[0] + (float)a[1] * (float)b[1];
#endif
}
__device__ __forceinline__ half2v h2(unsigned int u) { return __builtin_bit_cast(half2v, u); }

// 16-element f16 dot (one 32B chunk), fp32 acc
__device__ __forceinline__ float dot16h(const _Float16* __restrict__ w,
                                        const _Float16* __restrict__ x) {
  u32x4 a0 = *(const u32x4*)w;
  u32x4 a1 = *(const u32x4*)(w + 8);
  u32x4 b0 = *(const u32x4*)x;
  u32x4 b1 = *(const u32x4*)(x + 8);
  float acc = 0.f;
  acc = dot2f(h2(a0.x), h2(b0.x), acc);
  acc = dot2f(h2(a0.y), h2(b0.y), acc);
  acc = dot2f(h2(a0.z), h2(b0.z), acc);
  acc = dot2f(h2(a0.w), h2(b0.w), acc);
  acc = dot2f(h2(a1.x), h2(b1.x), acc);
  acc = dot2f(h2(a1.y), h2(b1.y), acc);
  acc = dot2f(h2(a1.z), h2(b1.z), acc);
  acc = dot2f(h2(a1.w), h2(b1.w), acc);
  return acc;
}

__device__ __forceinline__ float fast_tanh(float x) {
  x = fminf(15.f, fmaxf(-15.f, x));
  float e = __expf(2.f * x);
  return 1.f - __fdividef(2.f, e + 1.f);
}
__device__ __forceinline__ float fast_sigmoid(float x) {
  x = fminf(30.f, fmaxf(-30.f, x));
  float e = __expf(-x);
  return __fdividef(1.f, 1.f + e);
}
__device__ __forceinline__ unsigned short f2bf(float f) {  // RNE fp32->bf16
  unsigned int u = __builtin_bit_cast(unsigned int, f);
  return (unsigned short)((u + 0x7FFFu + ((u >> 16) & 1u)) >> 16);
}

// fence-free per-batch barrier (EXACTLY the R6/R7-proven protocol)
__device__ __forceinline__ void bar_step(int* __restrict__ ctr, int target) {
  __syncthreads();          // drains all waves' stores (vmcnt 0) before arrive
  if (threadIdx.x == 0) {
    __hip_atomic_fetch_add(ctr, 1, __ATOMIC_RELEASE, AGENT);
    while (__hip_atomic_load(ctr, __ATOMIC_RELAXED, AGENT) < target)
      __builtin_amdgcn_s_sleep(1);
    asm volatile("" ::: "memory");
  }
  __syncthreads();
}

// ---------------- setup kernels ----------------

__global__ void conv_f16_kernel(const float* __restrict__ s, _Float16* __restrict__ d, int n) {
  int i = blockIdx.x * 256 + threadIdx.x;
  if (i < n) d[i] = (_Float16)s[i];
}

__global__ void conv_bf16_kernel(const float* __restrict__ s, unsigned short* __restrict__ d, int n) {
  int i = blockIdx.x * 256 + threadIdx.x;
  if (i < n) d[i] = f2bf(s[i]);
}

// pack-transpose: out[k2][r] = f16pair(w[r][2k2], w[r][2k2+1]); coalesced writes
__global__ void packT_kernel(const float* __restrict__ w, unsigned int* __restrict__ out,
                             int R, int K) {
  int gid = blockIdx.x * 256 + threadIdx.x;
  int K2 = K >> 1;
  if (gid >= R * K2) return;
  int k2 = gid / R, r = gid - k2 * R;
  unsigned short ua = __builtin_bit_cast(unsigned short, (_Float16)w[(size_t)r * K + 2 * k2]);
  unsigned short ub = __builtin_bit_cast(unsigned short, (_Float16)w[(size_t)r * K + 2 * k2 + 1]);
  out[(size_t)k2 * R + r] = (unsigned int)ua | ((unsigned int)ub << 16);
}

// enc_proj_w (256,512) -> wT (512,256)
__global__ void transpose_kernel(const float* __restrict__ w, float* __restrict__ wT) {
  int i = blockIdx.x * 256 + threadIdx.x;
  if (i < 256 * 512) { int h = i >> 9, dd = i & 511; wT[dd * 256 + h] = w[i]; }
}

// proj[b,s,h] = enc_proj_b[h] + sum_d enc[s,b,d]*W[h,d]; write kvL[b][l=s][h] (f16)
__global__ __launch_bounds__(256) void proj_kernel(const float* __restrict__ enc,
                                                   const float* __restrict__ wT,
                                                   const float* __restrict__ pb,
                                                   _Float16* __restrict__ kvL) {
  int gid = blockIdx.x * 256 + threadIdx.x;
  int h4 = gid & 63;
  int bs = gid >> 6;                 // = s*32 + b (matches enc layout)
  if (bs >= NTP1 * NB) return;
  int s = bs >> 5, b = bs & 31;
  const float* er = enc + (size_t)bs * 512;
  float a0 = 0.f, a1 = 0.f, a2 = 0.f, a3 = 0.f;
  for (int d = 0; d < 512; d += 4) {
    f32x4 e4 = *(const f32x4*)(er + d);
    f32x4 w0 = *(const f32x4*)(wT + (size_t)(d + 0) * 256 + h4 * 4);
    f32x4 w1 = *(const f32x4*)(wT + (size_t)(d + 1) * 256 + h4 * 4);
    f32x4 w2 = *(const f32x4*)(wT + (size_t)(d + 2) * 256 + h4 * 4);
    f32x4 w3 = *(const f32x4*)(wT + (size_t)(d + 3) * 256 + h4 * 4);
    a0 = fmaf(e4.x, w0.x, a0); a1 = fmaf(e4.x, w0.y, a1); a2 = fmaf(e4.x, w0.z, a2); a3 = fmaf(e4.x, w0.w, a3);
    a0 = fmaf(e4.y, w1.x, a0); a1 = fmaf(e4.y, w1.y, a1); a2 = fmaf(e4.y, w1.z, a2); a3 = fmaf(e4.y, w1.w, a3);
    a0 = fmaf(e4.z, w2.x, a0); a1 = fmaf(e4.z, w2.y, a1); a2 = fmaf(e4.z, w2.z, a2); a3 = fmaf(e4.z, w2.w, a3);
    a0 = fmaf(e4.w, w3.x, a0); a1 = fmaf(e4.w, w3.y, a1); a2 = fmaf(e4.w, w3.z, a2); a3 = fmaf(e4.w, w3.w, a3);
  }
  int h = h4 * 4;
  a0 += pb[h + 0]; a1 += pb[h + 1]; a2 += pb[h + 2]; a3 += pb[h + 3];
  _Float16* dst = kvL + ((size_t)b * 512 + s) * 256 + h;
  dst[0] = (_Float16)a0; dst[1] = (_Float16)a1;
  dst[2] = (_Float16)a2; dst[3] = (_Float16)a3;
}

// kprojL[b][l][g] = sum_h kvL[b][l][h] * wk[g][h], for l < 257 (f16 out)
__global__ __launch_bounds__(256) void kproj0_kernel(const _Float16* __restrict__ kvL,
                                                     const float* __restrict__ wk,
                                                     _Float16* __restrict__ kprojL) {
  int b = blockIdx.x >> 3, gq = blockIdx.x & 7;
  __shared__ float wks[32][256];
  __shared__ float pk[32][8];
  int tid = threadIdx.x;
  for (int i = tid; i < 32 * 256; i += 256) {
    int g = i >> 8, h = i & 255;
    wks[g][h] = wk[(size_t)(gq * 32 + g) * 256 + h];
  }
  __syncthreads();
  {
    int l = tid;   // l in [0,256)
    float acc[32];
#pragma unroll
    for (int g = 0; g < 32; ++g) acc[g] = 0.f;
    for (int h = 0; h < 256; ++h) {
      float kvv = (float)kvL[((size_t)b * 512 + l) * 256 + h];
#pragma unroll
      for (int g = 0; g < 32; ++g) acc[g] = fmaf(kvv, wks[g][h], acc[g]);
    }
    for (int g = 0; g < 32; ++g)
      kprojL[((size_t)b * NL2 + l) * NH + gq * 32 + g] = (_Float16)acc[g];
  }
  // l == 256 handled cooperatively
  {
    int g = tid >> 3, hc = tid & 7;
    float acc = 0.f;
    for (int h = hc * 32; h < hc * 32 + 32; ++h)
      acc += (float)kvL[((size_t)b * 512 + 256) * 256 + h] * wks[g][h];
    pk[g][hc] = acc;
    __syncthreads();
    if (tid < 32) {
      float sv = 0.f;
      for (int c = 0; c < 8; ++c) sv += pk[tid][c];
      kprojL[((size_t)b * NL2 + 256) * NH + gq * 32 + tid] = (_Float16)sv;
    }
  }
}

// ---------------- cooperative scan: 8 WGs/batch, TWO exchanges/step ----------------
// WG (b = blk&31, s = blk>>5). kproj/kv are L-SLICED in LDS: WG s owns l in [64s,64s+64).
// Online-softmax commuted through Wih0: per-WG moments (m,Z) + y = Wih0_ctx @ ctx~.
// Exchange B1 (step boundary): h1' slices + q partials + kproj-row partials.
// Exchange B2 (mid-step): {m, Z, y[768], ui[768], uh[768]}.

__global__ __launch_bounds__(512) void scan_kernel(
    const int* __restrict__ x, const float* __restrict__ efs, const float* __restrict__ emb,
    const float* __restrict__ wv,
    const float* __restrict__ bih0, const float* __restrict__ bhh0,
    const float* __restrict__ bih1, const float* __restrict__ bhh1,
    const unsigned int* __restrict__ wqT, const unsigned int* __restrict__ wkT,
    const unsigned int* __restrict__ wih0T, const unsigned int* __restrict__ whh0T,
    const _Float16* __restrict__ wih1f, const _Float16* __restrict__ whh1f,
    const unsigned int* __restrict__ kvL_u, const unsigned int* __restrict__ kprojL_u,
    float* __restrict__ b1buf, float* __restrict__ b2buf,
    int* __restrict__ bars,
    unsigned short* __restrict__ outs_bf, float* __restrict__ attn_out) {
  __shared__ __align__(16) _Float16 kv16[64 * 258];  // l-slice: [64][256]+pad
  __shared__ __align__(16) _Float16 kp16[64 * 258];
  __shared__ __align__(16) _Float16 h0h[256], h1h[256], h1q[32];
  __shared__ __align__(16) float q_f[256], wvf[256], h0f[256], h1f[256];
  __shared__ __align__(16) float ctmp[2][256], ctxf[256], score_e[64], scr9[64 * 9];
  __shared__ __align__(16) float gi0f[768], gh0f[768], sgi[96], sgh[96];
  __shared__ __align__(16) float msz[2], mzv[16];
  __shared__ __align__(16) unsigned int ctxp_u[128], embp_u[16];

  int tid = threadIdx.x;
  int b = blockIdx.x & 31;
  int s = blockIdx.x >> 5;
  int* barB1 = bars + b * 32 + 0;
  int* barB2 = bars + b * 32 + 1;
  float* b2w = b2buf + ((size_t)(b * 8 + s)) * 2368;
  float* b1w = b1buf + ((size_t)(b * 8 + s)) * 576;

  // ---- init ----
  if (tid < 256) {
    float h0v = efs[(size_t)(0 * NB + b) * NH + tid] + efs[(size_t)(1 * NB + b) * NH + tid];
    float h1v = efs[(size_t)(2 * NB + b) * NH + tid] + efs[(size_t)(3 * NB + b) * NH + tid];
    h0f[tid] = h0v; h0h[tid] = (_Float16)h0v;
    h1f[tid] = h1v; h1h[tid] = (_Float16)h1v;
    wvf[tid] = wv[tid];
  }
  // LDS l-slices: l in [64s,64s+64); rows >= 257 zero
  for (int idx = tid; idx < 64 * 128; idx += 512) {
    int lr = idx >> 7, c = idx & 127;
    int l = 64 * s + lr;
    unsigned int kpv = 0u, kvv = 0u;
    if (l < NTP1) {
      kpv = kprojL_u[((size_t)b * 512 + l) * 128 + c];
      kvv = kvL_u[((size_t)b * 512 + l) * 128 + c];
    }
    ((unsigned int*)kp16)[lr * 129 + c] = kpv;
    ((unsigned int*)kv16)[lr * 129 + c] = kvv;
  }
  __syncthreads();
  if (tid < 32) h1q[tid] = h1h[32 * s + tid];
  __syncthreads();
  // pre-loop B1 partials: q from own h1 k-slice + h1 slice (kpp unused at t=0)
  if (tid < 256) {
    float a = 0.f;
#pragma unroll
    for (int i = 0; i < 16; ++i)
      a = dot2f(h2(wqT[(size_t)(16 * s + i) * 256 + tid]), h2(((const unsigned int*)h1q)[i]), a);
    astore(b1w + tid, a);
    if (tid < 16)
      astore(b1w + 512 + tid, __builtin_bit_cast(float, ((const unsigned int*)h1q)[tid]));
  }
  bar_step(barB1, 0);   // arrive only semantics: target 0 already satisfied -> pure arrive+pass

  for (int t = 0; t < NT; ++t) {
    int Lt = NTP1 + t;
    int tgt = 8 * (t + 1);
    // ---- wait B1 & assemble q, h1; owner appends kproj row & kv row ----
    if (tid == 0) {
      while (__hip_atomic_load(barB1, __ATOMIC_RELAXED, AGENT) < tgt)
        __builtin_amdgcn_s_sleep(1);
      asm volatile("" ::: "memory");
    }
    __syncthreads();
    if (tid < 256) {
      float a = 0.f;
#pragma unroll
      for (int sp = 0; sp < 8; ++sp) a += aload(b1buf + ((size_t)(b * 8 + sp)) * 576 + tid);
      q_f[tid] = a;
    } else if (tid < 384) {
      int k = tid - 256;
      int sp = k >> 4, i = k & 15;
      unsigned int u = __builtin_bit_cast(unsigned int,
          aload(b1buf + ((size_t)(b * 8 + sp)) * 576 + 512 + i));
      half2v p = h2(u);
      h1h[32 * sp + 2 * i] = p[0]; h1h[32 * sp + 2 * i + 1] = p[1];
      h1f[32 * sp + 2 * i] = (float)p[0]; h1f[32 * sp + 2 * i + 1] = (float)p[1];
    }
    __syncthreads();
    if (t >= 1) {
      int l_app = 256 + t;                 // append of h1 from step t-1
      if ((l_app >> 6) == s) {
        int lr = l_app - 64 * s;
        if (tid < 256) {
          float a = 0.f;
#pragma unroll
          for (int sp = 0; sp < 8; ++sp)
            a += aload(b1buf + ((size_t)(b * 8 + sp)) * 576 + 256 + tid);
          kp16[lr * 258 + tid] = (_Float16)a;
        } else {
          int h = tid - 256;
          kv16[lr * 258 + h] = h1h[h];
        }
      }
    }
    __syncthreads();
    // ---- scores (own l's, full g) + local softmax moments ----
    {
      int lr = tid >> 3, gc = tid & 7;
      const unsigned int* kpr = (const unsigned int*)kp16 + lr * 129 + gc * 16;
      const float* qg = q_f + gc * 32;
      const float* wg = wvf + gc * 32;
      float part = 0.f;
#pragma unroll
      for (int j = 0; j < 16; ++j) {
        half2v kp2 = h2(kpr[j]);
        part = fmaf(wg[2 * j], fast_tanh((float)kp2[0] + qg[2 * j]), part);
        part = fmaf(wg[2 * j + 1], fast_tanh((float)kp2[1] + qg[2 * j + 1]), part);
      }
      scr9[lr * 9 + gc] = part;
    }
    __syncthreads();
    if (tid < 64) {
      int l = 64 * s + tid;
      float sc = 0.f;
#pragma unroll
      for (int c = 0; c < 8; ++c) sc += scr9[tid * 9 + c];
      sc = (l < Lt) ? sc : -3.0e38f;
      float m = sc;
#pragma unroll
      for (int off = 32; off; off >>= 1) m = fmaxf(m, __shfl_xor(m, off, 64));
      float e = __expf(sc - m);
      score_e[tid] = e;
      float z = e;
#pragma unroll
      for (int off = 32; off; off >>= 1) z += __shfl_xor(z, off, 64);
      if (tid == 0) { msz[0] = m; msz[1] = z; }
    }
    __syncthreads();
    // ---- unnormalized ctx~ over own l's (kv rows >= Lt are zero) ----
    {
      int h = tid & 255, half = tid >> 8;
      const _Float16* kvb = kv16 + half * 32 * 258 + h;
      const float* ep = score_e + half * 32;
      float c = 0.f;
#pragma unroll 8
      for (int j = 0; j < 32; ++j) c = fmaf(ep[j], (float)kvb[j * 258], c);
      ctmp[half][h] = c;
    }
    __syncthreads();
    if (tid < 256) ctxf[tid] = ctmp[0][tid] + ctmp[1][tid];
    __syncthreads();
    if (tid < 128) {
      unsigned short lo = __builtin_bit_cast(unsigned short, (_Float16)ctxf[2 * tid]);
      unsigned short hi = __builtin_bit_cast(unsigned short, (_Float16)ctxf[2 * tid + 1]);
      ctxp_u[tid] = (unsigned int)lo | ((unsigned int)hi << 16);
    } else if (tid < 144) {
      int i = tid - 128;
      int tok = x[b * NT + t];
      unsigned short lo = __builtin_bit_cast(unsigned short, (_Float16)emb[(size_t)tok * 256 + 32 * s + 2 * i]);
      unsigned short hi = __builtin_bit_cast(unsigned short, (_Float16)emb[(size_t)tok * 256 + 32 * s + 2 * i + 1]);
      embp_u[i] = (unsigned int)lo | ((unsigned int)hi << 16);
    }
    __syncthreads();
    // ---- y = Wih0_ctx(full k) @ ctx~ ; ui/uh = k-sliced emb/gh0 partials ----
    {
      bool dual = (tid < 256);
      float y1 = 0.f, y2 = 0.f;
      const unsigned int* wp = wih0T + tid;
#pragma unroll 8
      for (int k2 = 0; k2 < 128; ++k2) {
        unsigned int cp = ctxp_u[k2];
        y1 = dot2f(h2(wp[(size_t)k2 * 768]), h2(cp), y1);
        if (dual) y2 = dot2f(h2(wp[(size_t)k2 * 768 + 512]), h2(cp), y2);
      }
      astore(b2w + tid, y1);
      if (dual) astore(b2w + 512 + tid, y2);
      float ui1 = 0.f, ui2 = 0.f, uh1 = 0.f, uh2 = 0.f;
      const unsigned int* h0p = (const unsigned int*)h0h;
#pragma unroll
      for (int i = 0; i < 16; ++i) {
        unsigned int ep = embp_u[i];
        unsigned int hp = h0p[16 * s + i];
        const unsigned int* we = wih0T + (size_t)(128 + 16 * s + i) * 768;
        const unsigned int* wh = whh0T + (size_t)(16 * s + i) * 768;
        ui1 = dot2f(h2(we[tid]), h2(ep), ui1);
        uh1 = dot2f(h2(wh[tid]), h2(hp), uh1);
        if (dual) {
          ui2 = dot2f(h2(we[512 + tid]), h2(ep), ui2);
          uh2 = dot2f(h2(wh[512 + tid]), h2(hp), uh2);
        }
      }
      astore(b2w + 768 + tid, ui1);
      astore(b2w + 1536 + tid, uh1);
      if (dual) {
        astore(b2w + 768 + 512 + tid, ui2);
        astore(b2w + 1536 + 512 + tid, uh2);
      }
      if (tid == 0) { astore(b2w + 2304, msz[0]); astore(b2w + 2305, msz[1]); }
    }
    bar_step(barB2, tgt);
    // ---- combine: global softmax moments + gates0 assembly (replicated) ----
    if (tid < 8) {
      const float* p = b2buf + ((size_t)(b * 8 + tid)) * 2368;
      mzv[2 * tid] = aload(p + 2304);
      mzv[2 * tid + 1] = aload(p + 2305);
    }
    __syncthreads();
    float M = mzv[0];
#pragma unroll
    for (int i = 1; i < 8; ++i) M = fmaxf(M, mzv[2 * i]);
    float alph[8];
    float Zg = 0.f;
#pragma unroll
    for (int sp = 0; sp < 8; ++sp) {
      alph[sp] = __expf(mzv[2 * sp] - M);
      Zg = fmaf(alph[sp], mzv[2 * sp + 1], Zg);
    }
    float rZ = __fdividef(1.f, Zg);
    {
      bool dual = (tid < 256);
      float gy1 = 0.f, gu1 = 0.f, gv1 = 0.f, gy2 = 0.f, gu2 = 0.f, gv2 = 0.f;
#pragma unroll
      for (int sp = 0; sp < 8; ++sp) {
        const float* p = b2buf + ((size_t)(b * 8 + sp)) * 2368;
        gy1 = fmaf(alph[sp], aload(p + tid), gy1);
        gu1 += aload(p + 768 + tid);
        gv1 += aload(p + 1536 + tid);
        if (dual) {
          gy2 = fmaf(alph[sp], aload(p + 512 + tid), gy2);
          gu2 += aload(p + 768 + 512 + tid);
          gv2 += aload(p + 1536 + 512 + tid);
        }
      }
      gi0f[tid] = gy1 * rZ + gu1 + bih0[tid];
      gh0f[tid] = gv1 + bhh0[tid];
      if (dual) {
        gi0f[512 + tid] = gy2 * rZ + gu2 + bih0[512 + tid];
        gh0f[512 + tid] = gv2 + bhh0[512 + tid];
      }
    }
    __syncthreads();
    if (tid < 256) {
      float r_ = fast_sigmoid(gi0f[tid] + gh0f[tid]);
      float z_ = fast_sigmoid(gi0f[256 + tid] + gh0f[256 + tid]);
      float n_ = fast_tanh(gi0f[512 + tid] + r_ * gh0f[512 + tid]);
      float hv = (1.f - z_) * n_ + z_ * h0f[tid];
      h0f[tid] = hv; h0h[tid] = (_Float16)hv;
    } else if (tid < 320) {
      int j = tid - 256;                 // own l = 64s+j; exact 0 at padding
      attn_out[((size_t)(b * NT + t)) * NL2 + 64 * s + j] = score_e[j] * alph[s] * rZ;
    }
    __syncthreads();
    // ---- GRU1 row-sliced (own 32 h outputs; full dots over h0', h1) ----
    if (tid < 384) {
      int rr = tid >> 2, sub = tid & 3;
      int g_ = rr >> 5, j = rr & 31;
      int grow = g_ * 256 + 32 * s + j;
      const _Float16* wi = wih1f + (size_t)grow * 256 + sub * 64;
      const _Float16* wh = whh1f + (size_t)grow * 256 + sub * 64;
      float gi = 0.f, gh = 0.f;
#pragma unroll
      for (int i = 0; i < 4; ++i) {
        gi += dot16h(wi + i * 16, h0h + sub * 64 + i * 16);
        gh += dot16h(wh + i * 16, h1h + sub * 64 + i * 16);
      }
      gi += __shfl_xor(gi, 1); gi += __shfl_xor(gi, 2);
      gh += __shfl_xor(gh, 1); gh += __shfl_xor(gh, 2);
      if (sub == 0) { sgi[rr] = gi; sgh[rr] = gh; }
    }
    __syncthreads();
    if (tid < 32) {
      int j = tid, hj = 32 * s + j;
      float r_ = fast_sigmoid(sgi[j] + bih1[hj] + sgh[j] + bhh1[hj]);
      float z_ = fast_sigmoid(sgi[32 + j] + bih1[256 + hj] + sgh[32 + j] + bhh1[256 + hj]);
      float n_ = fast_tanh(sgi[64 + j] + bih1[512 + hj] + r_ * (sgh[64 + j] + bhh1[512 + hj]));
      float hv = (1.f - z_) * n_ + z_ * h1f[hj];
      outs_bf[((size_t)(b * NT + t)) * NH + hj] = f2bf(hv);
      h1q[j] = (_Float16)hv;
    }
    __syncthreads();
    // ---- next-step B1 partials from own h1' slice ----
    if (t < NT - 1) {
      if (tid < 256) {
        float a = 0.f;
#pragma unroll
        for (int i = 0; i < 16; ++i)
          a = dot2f(h2(wqT[(size_t)(16 * s + i) * 256 + tid]), h2(((const unsigned int*)h1q)[i]), a);
        astore(b1w + tid, a);
        if (tid < 16)
          astore(b1w + 512 + tid, __builtin_bit_cast(float, ((const unsigned int*)h1q)[tid]));
      } else {
        int g = tid - 256;
        float a = 0.f;
#pragma unroll
        for (int i = 0; i < 16; ++i)
          a = dot2f(h2(wkT[(size_t)(16 * s + i) * 256 + g]), h2(((const unsigned int*)h1q)[i]), a);
        astore(b1w + 256 + g, a);
      }
      __syncthreads();
      if (tid == 0)
        __hip_atomic_fetch_add(barB1, 1, __ATOMIC_RELEASE, AGENT);
    }
  }
}

// ---------------- logits GEMM: C(8192x32000) = A(8192x256) * B^T + bias, bf16 MFMA ----------------

__global__ __launch_bounds__(256) void logits_gemm(const unsigned short* __restrict__ A,
                                                   const unsigned short* __restrict__ Bw,
                                                   const float* __restrict__ bias,
                                                   float* __restrict__ C) {
  __shared__ unsigned short As[128][88];
  __shared__ unsigned short Bs[128][88];
  int tid = threadIdx.x;
  int nt = blockIdx.x % 250, mt = blockIdx.x / 250;
  int m0 = mt * 128, n0 = nt * 128;
  int lane = tid & 63, w = tid >> 6;
  int wm = w & 1, wn = w >> 1;
  f32x4 acc[4][4];
#pragma unroll
  for (int m = 0; m < 4; ++m)
#pragma unroll
    for (int n = 0; n < 4; ++n) acc[m][n] = (f32x4)0.0f;

  int r0 = tid >> 3;
  int c0 = (tid & 7) * 8;
  for (int kt = 0; kt < 4; ++kt) {
    __syncthreads();
#pragma unroll
    for (int it = 0; it < 4; ++it) {
      int row = it * 32 + r0;
      u32x4 va = *(const u32x4*)(A + (size_t)(m0 + row) * 256 + kt * 64 + c0);
      u32x4 vb = *(const u32x4*)(Bw + (size_t)(n0 + row) * 256 + kt * 64 + c0);
      *(u32x4*)(&As[row][c0]) = va;
      *(u32x4*)(&Bs[row][c0]) = vb;
    }
    __syncthreads();
#pragma unroll
    for (int ks = 0; ks < 2; ++ks) {
      s16x8 af[4], bf[4];
#pragma unroll
      for (int m = 0; m < 4; ++m)
        af[m] = *(const s16x8*)(&As[wm * 64 + m * 16 + (lane & 15)][ks * 32 + (lane >> 4) * 8]);
#pragma unroll
      for (int n = 0; n < 4; ++n)
        bf[n] = *(const s16x8*)(&Bs[wn * 64 + n * 16 + (lane & 15)][ks * 32 + (lane >> 4) * 8]);
#pragma unroll
      for (int m = 0; m < 4; ++m)
#pragma unroll
        for (int n = 0; n < 4; ++n)
          acc[m][n] = __builtin_amdgcn_mfma_f32_16x16x32_bf16(af[m], bf[n], acc[m][n], 0, 0, 0);
    }
  }
#pragma unroll
  for (int n = 0; n < 4; ++n) {
    int col = n0 + wn * 64 + n * 16 + (lane & 15);
    float bv = bias[col];
#pragma unroll
    for (int m = 0; m < 4; ++m) {
      int rowb = m0 + wm * 64 + m * 16 + (lane >> 4) * 4;
#pragma unroll
      for (int r = 0; r < 4; ++r)
        C[(size_t)(rowb + r) * NV + col] = acc[m][n][r] + bv;
    }
  }
}

// ---------------- host launch ----------------

extern "C" void kernel_launch(void* const* d_in, const int* in_sizes, int n_in,
                              void* d_out, int out_size, void* d_ws, size_t ws_size,
                              hipStream_t stream) {
  const int*   x    = (const int*)d_in[0];
  const float* enc  = (const float*)d_in[1];
  const float* efs  = (const float*)d_in[2];
  const float* emb  = (const float*)d_in[3];
  const float* epw  = (const float*)d_in[4];
  const float* epb  = (const float*)d_in[5];
  const float* wq   = (const float*)d_in[6];
  const float* wk   = (const float*)d_in[7];
  const float* wv   = (const float*)d_in[8];
  const float* wih0 = (const float*)d_in[9];
  const float* whh0 = (const float*)d_in[10];
  const float* bih0 = (const float*)d_in[11];
  const float* bhh0 = (const float*)d_in[12];
  const float* wih1 = (const float*)d_in[13];
  const float* whh1 = (const float*)d_in[14];
  const float* bih1 = (const float*)d_in[15];
  const float* bhh1 = (const float*)d_in[16];
  const float* dw   = (const float*)d_in[17];
  const float* db   = (const float*)d_in[18];

  // workspace layout (bytes). The 16.38MB dwbf16 region is aliased during setup/scan by:
  //   wqT, wkT, wih0T, whh0T, wih1f, whh1f, kvL — all dead before conv_bf16 runs.
  const size_t o_alias  = 0;                            // 16,384,000
  const size_t a_wqT    = 0;                            // 131,072
  const size_t a_wkT    = a_wqT + 131072;               // 131,072
  const size_t a_wih0T  = a_wkT + 131072;               // 786,432
  const size_t a_whh0T  = a_wih0T + 786432;             // 393,216
  const size_t a_wih1f  = a_whh0T + 393216;             // 393,216
  const size_t a_whh1f  = a_wih1f + 393216;             // 393,216
  const size_t a_kvL    = a_whh1f + 393216;             // 8,388,608  (ends at 10,616,832)
  const size_t o_wT     = o_alias + 16384000;           // 524,288
  const size_t o_kprojL = o_wT + 524288;                // 8,388,608
  const size_t o_outs   = o_kprojL + 8388608;           // 4,194,304
  const size_t o_b1     = o_outs + 4194304;             // 32*8*576*4  = 589,824
  const size_t o_b2     = o_b1 + 589824;                // 32*8*2368*4 = 2,424,832
  const size_t o_bar    = o_b2 + 2424832;               // 4,096
  const size_t need     = o_bar + 4096;                 // ~32.5 MB
  if (ws_size < need) return;  // fail visibly rather than corrupt

  char* ws = (char*)d_ws;
  unsigned short* dwbf16 = (unsigned short*)(ws + o_alias);
  unsigned int* wqT   = (unsigned int*)(ws + a_wqT);
  unsigned int* wkT   = (unsigned int*)(ws + a_wkT);
  unsigned int* wih0T = (unsigned int*)(ws + a_wih0T);
  unsigned int* whh0T = (unsigned int*)(ws + a_whh0T);
  _Float16* wih1f     = (_Float16*)(ws + a_wih1f);
  _Float16* whh1f     = (_Float16*)(ws + a_whh1f);
  _Float16* kvL       = (_Float16*)(ws + a_kvL);
  float* wT           = (float*)(ws + o_wT);
  _Float16* kprojL    = (_Float16*)(ws + o_kprojL);
  unsigned short* outs_bf = (unsigned short*)(ws + o_outs);
  float* b1buf        = (float*)(ws + o_b1);
  float* b2buf        = (float*)(ws + o_b2);
  int* bars           = (int*)(ws + o_bar);

  float* logits = (float*)d_out;
  float* attn_out = logits + (size_t)NB * NT * NV;

  hipMemsetAsync(ws + o_bar, 0, 4096, stream);

  // weight prep
  packT_kernel<<<(256 * 128 + 255) / 256, 256, 0, stream>>>(wq, wqT, 256, 256);
  packT_kernel<<<(256 * 128 + 255) / 256, 256, 0, stream>>>(wk, wkT, 256, 256);
  packT_kernel<<<(768 * 256 + 255) / 256, 256, 0, stream>>>(wih0, wih0T, 768, 512);
  packT_kernel<<<(768 * 128 + 255) / 256, 256, 0, stream>>>(whh0, whh0T, 768, 256);
  conv_f16_kernel<<<(196608 + 255) / 256, 256, 0, stream>>>(wih1, wih1f, 196608);
  conv_f16_kernel<<<(196608 + 255) / 256, 256, 0, stream>>>(whh1, whh1f, 196608);
  transpose_kernel<<<(131072 + 255) / 256, 256, 0, stream>>>(epw, wT);

  // encoder projection -> kvL[b][l][h] (f16), then key projections -> kprojL[b][l][g] (f16)
  proj_kernel<<<(NTP1 * NB * 64) / 256, 256, 0, stream>>>(enc, wT, epb, kvL);
  kproj0_kernel<<<NB * 8, 256, 0, stream>>>(kvL, wk, kprojL);

  // cooperative scan: 256 WGs (8 per batch), 512 threads each
  scan_kernel<<<256, 512, 0, stream>>>(x, efs, emb, wv, bih0, bhh0, bih1, bhh1,
                                       wqT, wkT, wih0T, whh0T, wih1f, whh1f,
                                       (const unsigned int*)kvL, (const unsigned int*)kprojL,
                                       b1buf, b2buf, bars,
                                       outs_bf, attn_out);

  // now safe to overwrite the alias region with bf16 dense_w
  conv_bf16_kernel<<<(8192000 + 255) / 256, 256, 0, stream>>>(dw, dwbf16, 8192000);

  // final big GEMM: logits
  logits_gemm<<<(NB * NT / 128) * (NV / 128), 256, 0, stream>>>(outs_bf, dwbf16, db, logits);
}